// Round 10
// baseline (194.405 us; speedup 1.0000x reference)
//
#include <hip/hip_runtime.h>
#include <math.h>

#define ALPHA 0.2f
#define LOG2E 1.44269504089f

typedef __attribute__((ext_vector_type(8))) short bf16x8;
typedef __attribute__((ext_vector_type(4))) float f32x4;

__device__ __forceinline__ float elu1(float x)  { return x > 0.f ? x : (__expf(x) - 1.f); }

// round-to-nearest-even f32 -> bf16 (finite values only)
__device__ __forceinline__ unsigned short f2bf(float x) {
    unsigned u = __float_as_uint(x);
    return (unsigned short)((u + 0x7fffu + ((u >> 16) & 1u)) >> 16);
}
__device__ __forceinline__ unsigned pkbf16(float a, float b) {
    return (unsigned)f2bf(a) | ((unsigned)f2bf(b) << 16);
}
__device__ __forceinline__ float bfs(unsigned short v) { return __uint_as_float((unsigned)v << 16); }
// round-half-up pack (a->lo, b->hi) via single v_perm on bias-added bits
__device__ __forceinline__ unsigned pkbf_rhu(float a, float b) {
    unsigned ua = __float_as_uint(a) + 0x8000u;
    unsigned ub = __float_as_uint(b) + 0x8000u;
    return __builtin_amdgcn_perm(ub, ua, 0x07060302u);
}

// ---------------------------------------------------------------------------
// Prep (single launch): blocks 0..287 transpose weights (W [z][K][128] f32 ->
// WT [z][128][K] bf16 via LDS 64x64 tiles; z<8: Wh K=256, z==8: Wo K=1024);
// blocks 288..2335 convert x f32 -> bf16 (1024 elems each).
// ---------------------------------------------------------------------------
__global__ __launch_bounds__(256) void prep_all(
    const float* __restrict__ x, const float* __restrict__ Wh,
    const float* __restrict__ Wo, unsigned short* __restrict__ xb,
    unsigned short* __restrict__ WhT, unsigned short* __restrict__ WoT)
{
    __shared__ float T[64][65];
    const int tid = threadIdx.x;
    const int gid = blockIdx.x;

    if (gid >= 288) {                 // x convert
        int idx = (gid - 288) * 1024 + tid * 4;
        float4 v = *(const float4*)(x + idx);
        uint2 o = make_uint2(pkbf16(v.x, v.y), pkbf16(v.z, v.w));
        *(uint2*)(xb + idx) = o;
        return;
    }

    const int z = gid >> 5, rem = gid & 31;
    const int bx = rem & 15, by = rem >> 4;
    const int K = (z < 8) ? 256 : 1024;
    if (bx * 64 >= K) return;
    const float* in = (z < 8) ? (Wh + (size_t)z * K * 128) : Wo;
    unsigned short* out = (z < 8) ? (WhT + (size_t)z * 128 * K) : WoT;
    const int k0 = bx * 64, n0 = by * 64;

    const int kr = tid >> 4, nc = (tid & 15) * 4;
#pragma unroll
    for (int s = 0; s < 4; ++s) {
        float4 v = *(const float4*)(in + (size_t)(k0 + kr + s * 16) * 128 + n0 + nc);
        T[kr + s * 16][nc]     = v.x;
        T[kr + s * 16][nc + 1] = v.y;
        T[kr + s * 16][nc + 2] = v.z;
        T[kr + s * 16][nc + 3] = v.w;
    }
    __syncthreads();
    const int nr0 = tid >> 3, kc = (tid & 7) * 8;
#pragma unroll
    for (int s = 0; s < 2; ++s) {
        int nr = nr0 + s * 32;
        unsigned pk[4];
#pragma unroll
        for (int q = 0; q < 4; ++q)
            pk[q] = pkbf16(T[kc + 2 * q][nr], T[kc + 2 * q + 1][nr]);
        *(uint4*)(out + (size_t)(n0 + nr) * K + k0 + kc) = make_uint4(pk[0], pk[1], pk[2], pk[3]);
    }
}

// ---------------------------------------------------------------------------
// LDS-staged bf16 MFMA GEMM with transposed C store (C^T via aliased LDS ->
// coalesced uint4 stores). DOF=1 (BN==128): fused f1/f2 dot-products from the
// resident C^T head tile. A bf16 [M][K], Bt bf16 [n][K], Ct bf16 [n][8192].
// ---------------------------------------------------------------------------
template <int BM, int BN, int WM, int WN, int DOF>
__global__ __launch_bounds__(256) void gemm_t(
    const unsigned short* __restrict__ A, const unsigned short* __restrict__ Bt,
    unsigned short* __restrict__ Ct, int K,
    const float* __restrict__ aV, float* __restrict__ f1g, float* __restrict__ f2g)
{
    const int RM = WM / 16, RN = WN / 16;
    const int NCA = BM * 8 / 256, NCB = BN * 8 / 256;
    __shared__ __align__(16) unsigned short SAB[(BM + BN) * 72];
    unsigned short (*As)[72] = (unsigned short(*)[72])SAB;
    unsigned short (*Bs)[72] = (unsigned short(*)[72])(SAB + BM * 72);
    unsigned short (*Cs)[BM + 8] = (unsigned short(*)[BM + 8])SAB;   // alias
    float* redf = (float*)(SAB + BN * (BM + 8));                     // after Cs

    const int tid = threadIdx.x;
    const int w = tid >> 6, lane = tid & 63;
    const int n16 = lane & 15, quad = lane >> 4;
    const int WX = BM / WM;
    const int wm = (w % WX) * WM, wn = (w / WX) * WN;
    const int m0 = blockIdx.x * BM, n0 = blockIdx.y * BN;

    f32x4 acc[RM][RN];
#pragma unroll
    for (int mm = 0; mm < RM; ++mm)
#pragma unroll
        for (int nn = 0; nn < RN; ++nn) acc[mm][nn] = (f32x4){0.f, 0.f, 0.f, 0.f};

    uint4 ra[NCA], rb[NCB];
#pragma unroll
    for (int i = 0; i < NCA; ++i) {
        int c = tid * NCA + i, r = c >> 3, cc = (c & 7) * 8;
        ra[i] = *(const uint4*)(A + (size_t)(m0 + r) * K + cc);
    }
#pragma unroll
    for (int i = 0; i < NCB; ++i) {
        int c = tid * NCB + i, r = c >> 3, cc = (c & 7) * 8;
        rb[i] = *(const uint4*)(Bt + (size_t)(n0 + r) * K + cc);
    }

    const int nk = K >> 6;
    for (int kt = 0; kt < nk; ++kt) {
        __syncthreads();
#pragma unroll
        for (int i = 0; i < NCA; ++i) {
            int c = tid * NCA + i, r = c >> 3, cc = (c & 7) * 8;
            *(uint4*)&As[r][cc] = ra[i];
        }
#pragma unroll
        for (int i = 0; i < NCB; ++i) {
            int c = tid * NCB + i, r = c >> 3, cc = (c & 7) * 8;
            *(uint4*)&Bs[r][cc] = rb[i];
        }
        __syncthreads();
        if (kt + 1 < nk) {
            int k0 = (kt + 1) * 64;
#pragma unroll
            for (int i = 0; i < NCA; ++i) {
                int c = tid * NCA + i, r = c >> 3, cc = (c & 7) * 8;
                ra[i] = *(const uint4*)(A + (size_t)(m0 + r) * K + k0 + cc);
            }
#pragma unroll
            for (int i = 0; i < NCB; ++i) {
                int c = tid * NCB + i, r = c >> 3, cc = (c & 7) * 8;
                rb[i] = *(const uint4*)(Bt + (size_t)(n0 + r) * K + k0 + cc);
            }
        }
#pragma unroll
        for (int ks = 0; ks < 2; ++ks) {
            bf16x8 am[RM], bn[RN];
#pragma unroll
            for (int mm = 0; mm < RM; ++mm)
                am[mm] = *(const bf16x8*)&As[wm + mm * 16 + n16][ks * 32 + quad * 8];
#pragma unroll
            for (int nn = 0; nn < RN; ++nn)
                bn[nn] = *(const bf16x8*)&Bs[wn + nn * 16 + n16][ks * 32 + quad * 8];
#pragma unroll
            for (int mm = 0; mm < RM; ++mm)
#pragma unroll
                for (int nn = 0; nn < RN; ++nn)
                    acc[mm][nn] = __builtin_amdgcn_mfma_f32_16x16x32_bf16(
                        am[mm], bn[nn], acc[mm][nn], 0, 0, 0);
        }
    }

    __syncthreads();   // all LDS frag reads done before Cs aliases As/Bs

    // --- epilogue: acc -> LDS bf16 tile (C^T layout: Cs[n][m]) ---
#pragma unroll
    for (int nn = 0; nn < RN; ++nn) {
        int n = wn + nn * 16 + n16;
#pragma unroll
        for (int mm = 0; mm < RM; ++mm) {
            int m = wm + mm * 16 + quad * 4;
            f32x4 a = acc[mm][nn];
            ushort4 o = make_ushort4(f2bf(a[0]), f2bf(a[1]), f2bf(a[2]), f2bf(a[3]));
            *(ushort4*)&Cs[n][m] = o;
        }
    }
    __syncthreads();

    // --- coalesced store: row n = BM shorts contiguous, uint4 chunks ---
    const int CHUNKS = BM * 2 / 16;
    const int RPP = 256 / CHUNKS;
    const int row = tid / CHUNKS, ch = tid % CHUNKS;
#pragma unroll
    for (int s = 0; s < BN / RPP; ++s) {
        int n = row + s * RPP;
        *(uint4*)(Ct + (size_t)(n0 + n) * 8192 + m0 + ch * 8) =
            *(const uint4*)&Cs[n][ch * 8];
    }

    // --- fused f1/f2 (one head resident: BN==128) ---
    if (DOF) {
        const int mloc = tid & 63, fq = tid >> 6;
        const float* az = aV + blockIdx.y * 256;
        float s1 = 0.f, s2 = 0.f;
#pragma unroll 8
        for (int k = 0; k < 32; ++k) {
            int f = fq * 32 + k;
            float h = bfs(Cs[f][mloc]);
            s1 += h * az[f];
            s2 += h * az[128 + f];
        }
        *(float2*)&redf[(fq * 64 + mloc) * 2] = make_float2(s1, s2);
        __syncthreads();
        if (tid < 64) {
            float a1 = redf[tid * 2]       + redf[(64 + tid) * 2]
                     + redf[(128 + tid) * 2] + redf[(192 + tid) * 2];
            float a2 = redf[tid * 2 + 1]       + redf[(64 + tid) * 2 + 1]
                     + redf[(128 + tid) * 2 + 1] + redf[(192 + tid) * 2 + 1];
            f1g[(size_t)blockIdx.y * 8192 + m0 + tid] = a1;
            f2g[(size_t)blockIdx.y * 8192 + m0 + tid] = a2;
        }
    }
}

// ---------------------------------------------------------------------------
// MFMA attention v6 — exp-free inner loop, JT=32 tiles, double-buffered LDS,
// NI=1 (wave = 16 i x 128 f) -> grid 2x bigger = 4 blocks/CU (was 2; the
// per-tile barrier stalls ran at 25% occupancy before).
// p_ij = exp2(lrelu(f1+f2)L - mc) = max(Ai*u_j, A2i*v_j)   (exp2 monotone)
// lsum via ones-column MFMA. XCD-aware grid: slice coord on blockIdx.x so
// same-slice blocks land on one XCD and share its L2 copy of the slice.
// L1 (OUTBF=1): grid (8=hy, 16, 8=bz); L2 (OUTBF=0): grid (8=bz, 16, 1).
// ---------------------------------------------------------------------------
template <int OUTBF>
__global__ __launch_bounds__(256) void attn5(
    const unsigned short* __restrict__ hT, const float* __restrict__ f1g,
    const float* __restrict__ f2g, float* __restrict__ outf,
    unsigned short* __restrict__ outb, int elu2)
{
    const int N = 1024, JT = 32, JP = 40;
    __shared__ __align__(16) unsigned short hls[2][128][JP];
    __shared__ float ul[1024], vl[1024];
    __shared__ float wred[4];

    const int tid = threadIdx.x;
    const int w = tid >> 6, lane = tid & 63;
    const int n16 = lane & 15, quad = lane >> 4;
    const int hy = OUTBF ? blockIdx.x : 0;
    const int bz = OUTBF ? blockIdx.z : blockIdx.x;
    const int hb = hy * 8 + bz;
    const int iw0 = blockIdx.y * 64 + w * 16;

    // u/v tables + block max of f2L
    {
        int j4 = tid * 4;
        float4 fv = *(const float4*)(f2g + (size_t)hb * N + j4);
        fv.x *= LOG2E; fv.y *= LOG2E; fv.z *= LOG2E; fv.w *= LOG2E;
        float m4 = fmaxf(fmaxf(fv.x, fv.y), fmaxf(fv.z, fv.w));
#pragma unroll
        for (int off = 32; off; off >>= 1) m4 = fmaxf(m4, __shfl_xor(m4, off));
        if (lane == 0) wred[w] = m4;
        float4 uu, vv;
        uu.x = __builtin_amdgcn_exp2f(fv.x); vv.x = __builtin_amdgcn_exp2f(ALPHA * fv.x);
        uu.y = __builtin_amdgcn_exp2f(fv.y); vv.y = __builtin_amdgcn_exp2f(ALPHA * fv.y);
        uu.z = __builtin_amdgcn_exp2f(fv.z); vv.z = __builtin_amdgcn_exp2f(ALPHA * fv.z);
        uu.w = __builtin_amdgcn_exp2f(fv.w); vv.w = __builtin_amdgcn_exp2f(ALPHA * fv.w);
        *(float4*)&ul[j4] = uu;
        *(float4*)&vl[j4] = vv;
    }

    float f1L = f1g[(size_t)hb * N + iw0 + n16] * LOG2E;

    // staging: thread covers rows sr0, sr0+64; 8-j chunk sc
    const unsigned short* gsrc = hT + (size_t)hy * 128 * 8192 + bz * 1024;
    const int sr0 = tid >> 2, sc = (tid & 3) * 8;

    bf16x8 stg[2];
    stg[0] = *(const bf16x8*)(gsrc + (size_t)sr0 * 8192 + sc);
    stg[1] = *(const bf16x8*)(gsrc + (size_t)(sr0 + 64) * 8192 + sc);

    __syncthreads();   // ul/vl/wred visible
    const float f2mL = fmaxf(fmaxf(wred[0], wred[1]), fmaxf(wred[2], wred[3]));
    float Ai, A2i;
    {
        float s = f1L + f2mL;
        float mc = fmaxf(s, ALPHA * s);
        Ai  = __builtin_amdgcn_exp2f(f1L - mc);
        A2i = __builtin_amdgcn_exp2f(ALPHA * f1L - mc);
    }

    f32x4 acc[8], accl;
    accl = (f32x4){0.f, 0.f, 0.f, 0.f};
#pragma unroll
    for (int t = 0; t < 8; ++t) acc[t] = (f32x4){0.f, 0.f, 0.f, 0.f};
    bf16x8 ones;
    { union { bf16x8 v; unsigned u[4]; } o;
      o.u[0] = o.u[1] = o.u[2] = o.u[3] = 0x3F803F80u; ones = o.v; }

    // stage tile 0 into buf 0
    *(bf16x8*)&hls[0][sr0][sc] = stg[0];
    *(bf16x8*)&hls[0][sr0 + 64][sc] = stg[1];
    __syncthreads();

    for (int jt = 0; jt < N / JT; ++jt) {
        const int cur = jt & 1;
        if (jt + 1 < N / JT) {
            int j0n = (jt + 1) * JT;
            stg[0] = *(const bf16x8*)(gsrc + (size_t)sr0 * 8192 + j0n + sc);
            stg[1] = *(const bf16x8*)(gsrc + (size_t)(sr0 + 64) * 8192 + j0n + sc);
        }
        const int jb = jt * JT + quad * 8;
        float4 u0 = *(const float4*)&ul[jb], u1 = *(const float4*)&ul[jb + 4];
        float4 v0 = *(const float4*)&vl[jb], v1 = *(const float4*)&vl[jb + 4];
        float uj[8] = {u0.x, u0.y, u0.z, u0.w, u1.x, u1.y, u1.z, u1.w};
        float vj[8] = {v0.x, v0.y, v0.z, v0.w, v1.x, v1.y, v1.z, v1.w};

        bf16x8 afr;
        {
            union { bf16x8 v; unsigned u[4]; } cvt;
#pragma unroll
            for (int q = 0; q < 4; ++q) {
                float p0 = fmaxf(Ai * uj[2 * q],     A2i * vj[2 * q]);
                float p1 = fmaxf(Ai * uj[2 * q + 1], A2i * vj[2 * q + 1]);
                cvt.u[q] = pkbf_rhu(p0, p1);
            }
            afr = cvt.v;
        }
#pragma unroll
        for (int t = 0; t < 8; ++t) {
            bf16x8 bfr = *(const bf16x8*)&hls[cur][t * 16 + n16][quad * 8];
            acc[t] = __builtin_amdgcn_mfma_f32_16x16x32_bf16(afr, bfr, acc[t], 0, 0, 0);
        }
        accl = __builtin_amdgcn_mfma_f32_16x16x32_bf16(afr, ones, accl, 0, 0, 0);

        if (jt + 1 < N / JT) {
            *(bf16x8*)&hls[1 - cur][sr0][sc] = stg[0];
            *(bf16x8*)&hls[1 - cur][sr0 + 64][sc] = stg[1];
        }
        __syncthreads();
    }

    // epilogue: C/D layout col=lane&15 (f), row=quad*4+reg (i); lsum in accl
#pragma unroll
    for (int r = 0; r < 4; ++r) {
        float inv = 1.f / accl[r];
        int i = iw0 + quad * 4 + r;
#pragma unroll
        for (int t = 0; t < 8; ++t) {
            float tv = acc[t][r] * inv;
            tv = elu1(tv);
            if (OUTBF) {
                outb[(size_t)(bz * 1024 + i) * 1024 + hy * 128 + t * 16 + n16] = f2bf(tv);
            } else {
                if (elu2) tv = elu1(tv);
                outf[(size_t)(bz * 1024 + i) * 128 + t * 16 + n16] = tv;
            }
        }
    }
}

// ---------------------------------------------------------------------------
// B=8, N=1024, D=256, H=8, F=128
// ---------------------------------------------------------------------------
extern "C" void kernel_launch(void* const* d_in, const int* in_sizes, int n_in,
                              void* d_out, int out_size, void* d_ws, size_t ws_size,
                              hipStream_t stream)
{
    const float* x  = (const float*)d_in[0];
    const float* Wh = (const float*)d_in[2];
    const float* ah = (const float*)d_in[3];
    const float* Wo = (const float*)d_in[4];
    const float* ao = (const float*)d_in[5];
    float* out = (float*)d_out;

    unsigned short* xb  = (unsigned short*)d_ws;       // [8192][256]   4 MB
    unsigned short* WhT = xb + 2097152;                // [1024][256]   512 KB
    unsigned short* WoT = WhT + 262144;                // [128][1024]   256 KB
    unsigned short* h1T = WoT + 131072;                // [8][128][8192] 16 MB
    unsigned short* xcb = h1T + 8388608;               // [8192][1024]  16 MB
    unsigned short* h2T = xcb + 8388608;               // [128][8192]   2 MB
    float* f1a  = (float*)(h2T + 1048576);             // [8][8192]
    float* f2a  = f1a + 65536;                         // [8][8192]
    float* f1b  = f2a + 65536;                         // [8192]
    float* f2b  = f1b + 8192;                          // [8192]

    // prep: weight transposes + x->bf16 in one launch
    prep_all<<<2336, 256, 0, stream>>>(x, Wh, Wo, xb, WhT, WoT);

    // Layer 1: GEMM (bf16 A) + fused f1/f2 epilogue
    gemm_t<64, 128, 32, 64, 1><<<dim3(128, 8), 256, 0, stream>>>(
        xb, WhT, h1T, 256, ah, f1a, f2a);
    attn5<1><<<dim3(8, 16, 8), 256, 0, stream>>>(h1T, f1a, f2a, nullptr, xcb, 0);

    // Layer 2: GEMM (BN=128 -> fused f1/f2, fdot kernel deleted)
    gemm_t<64, 128, 32, 64, 1><<<dim3(128, 1), 256, 0, stream>>>(
        xcb, WoT, h2T, 1024, ao, f1b, f2b);
    attn5<0><<<dim3(8, 16, 1), 256, 0, stream>>>(h2T, f1b, f2b, out, nullptr, 1);
}